// Round 1
// baseline (7438.258 us; speedup 1.0000x reference)
//
#include <hip/hip_runtime.h>
#include <math.h>

constexpr int NN = 50000;
constexpr int NE = 1600000;
constexpr float LN_EPS = 1e-5f;

// ---------------------------------------------------------------- degree / dis
__global__ void deg_kernel(const int* __restrict__ col, float* __restrict__ deg)
{
    int e = blockIdx.x * 256 + threadIdx.x;
    if (e < NE) atomicAdd(&deg[col[e]], 1.0f);
}

__global__ void dis_kernel(float* __restrict__ deg)
{
    int i = blockIdx.x * 256 + threadIdx.x;
    if (i < NN) deg[i] = rsqrtf(deg[i] + 1.0f);   // +1 = self loop
}

// ---------------------------------------------------------------- weight pack
// Wt[k*DO + o], k = f*5 + g ; g<4 -> sw[o][f*4+g], g==4 -> bw[o][f]
__global__ void pack_weights(const float* __restrict__ sw, const float* __restrict__ bw,
                             float* __restrict__ wt, int D, int DO)
{
    int idx = blockIdx.x * 256 + threadIdx.x;
    int K = D * 5;
    if (idx >= K * DO) return;
    int k = idx / DO, o = idx - k * DO;
    int f = k / 5,  g = k - f * 5;
    wt[idx] = (g < 4) ? sw[o * D * 4 + f * 4 + g] : bw[o * D + f];
}

// ---------------------------------------------------------------- FastKAN layer
// block = 128 threads, 8 nodes/block. D multiple of 128, sources are 128-wide.
template<int D, int DO>
__global__ __launch_bounds__(128) void fkan_kernel(
    const float* __restrict__ s0, const float* __restrict__ s1, const float* __restrict__ s2,
    const float* __restrict__ ln_g, const float* __restrict__ ln_b,
    const float* __restrict__ wt, const float* __restrict__ sb, const float* __restrict__ bb,
    float* __restrict__ out)
{
    constexpr int K  = D * 5;
    constexpr int NB = 8;
    __shared__ float feat[K * NB];           // feat[k*8 + node]
    const int tid   = threadIdx.x;
    const int node0 = blockIdx.x * NB;

    // ---- phase 1: LN + RBF basis + SiLU into LDS (16 lanes per node)
    {
        const int ng   = tid >> 4;
        const int ln   = tid & 15;
        const int node = node0 + ng;
        constexpr int FPT = D / 16;
        float v[FPT];
        float sum = 0.f;
        #pragma unroll
        for (int j = 0; j < FPT; ++j) {
            int f = ln * FPT + j;
            const float* s = (D == 128) ? s0 : ((f < 128) ? s0 : (f < 256) ? s1 : s2);
            v[j] = s[node * 128 + (f & 127)];
            sum += v[j];
        }
        #pragma unroll
        for (int m = 1; m < 16; m <<= 1) sum += __shfl_xor(sum, m);
        float mu = sum * (1.0f / D);
        float var = 0.f;
        #pragma unroll
        for (int j = 0; j < FPT; ++j) { float d = v[j] - mu; var += d * d; }
        #pragma unroll
        for (int m = 1; m < 16; m <<= 1) var += __shfl_xor(var, m);
        float rstd = rsqrtf(var * (1.0f / D) + LN_EPS);
        #pragma unroll
        for (int j = 0; j < FPT; ++j) {
            int f = ln * FPT + j;
            float hn = (v[j] - mu) * rstd * ln_g[f] + ln_b[f];
            float* fp = &feat[(f * 5) * NB + ng];
            #pragma unroll
            for (int g = 0; g < 4; ++g) {
                float t = (hn - (-2.0f + (4.0f / 3.0f) * g)) * 0.75f;   // /DENOM
                fp[g * NB] = __expf(-t * t);
            }
            fp[4 * NB] = v[j] / (1.0f + __expf(-v[j]));                 // silu(raw h)
        }
    }
    __syncthreads();

    // ---- phase 2: out[n][o] = feat[n] . Wt[:,o] + sb[o] + bb[o]
    if constexpr (DO == 128) {
        const int o = tid;
        float acc[8] = {0, 0, 0, 0, 0, 0, 0, 0};
        for (int k = 0; k < K; ++k) {
            float w = wt[k * DO + o];
            float4 fa = *(const float4*)&feat[k * 8];
            float4 fb = *(const float4*)&feat[k * 8 + 4];
            acc[0] += fa.x * w; acc[1] += fa.y * w; acc[2] += fa.z * w; acc[3] += fa.w * w;
            acc[4] += fb.x * w; acc[5] += fb.y * w; acc[6] += fb.z * w; acc[7] += fb.w * w;
        }
        float c = sb[o] + bb[o];
        #pragma unroll
        for (int n = 0; n < 8; ++n) out[(node0 + n) * DO + o] = acc[n] + c;
    } else {
        if (tid < 2 * DO) {
            const int o    = tid % DO;
            const int half = tid / DO;
            float acc[4] = {0, 0, 0, 0};
            for (int k = 0; k < K; ++k) {
                float w = wt[k * DO + o];
                float4 fa = *(const float4*)&feat[k * 8 + half * 4];
                acc[0] += fa.x * w; acc[1] += fa.y * w; acc[2] += fa.z * w; acc[3] += fa.w * w;
            }
            float c = sb[o] + bb[o];
            #pragma unroll
            for (int n = 0; n < 4; ++n) out[(node0 + half * 4 + n) * DO + o] = acc[n] + c;
        }
    }
}

// ---------------------------------------------------------------- propagate
template<int DO>
__global__ void agg_init(const float* __restrict__ dis, const float* __restrict__ hw,
                         const float* __restrict__ bias, float* __restrict__ agg)
{
    int idx = blockIdx.x * 256 + threadIdx.x;
    if (idx >= NN * DO) return;
    int n = idx / DO;
    int o = idx - n * DO;
    float dv = dis[n];
    agg[idx] = dv * dv * hw[idx] + bias[o];     // self-loop + conv bias
}

template<int DO>
__global__ void edge_kernel(const int* __restrict__ ei, const float* __restrict__ dis,
                            const float* __restrict__ hw, float* __restrict__ agg)
{
    constexpr int TPE = DO / 4;
    int t = blockIdx.x * blockDim.x + threadIdx.x;
    int e = t / TPE;
    if (e >= NE) return;
    int l = t - e * TPE;
    int r = ei[e];
    int c = ei[NE + e];
    float w = dis[r] * dis[c];
    float4 v = *(const float4*)&hw[r * DO + l * 4];
    float* dst = &agg[c * DO + l * 4];
    atomicAdd(dst + 0, w * v.x);
    atomicAdd(dst + 1, w * v.y);
    atomicAdd(dst + 2, w * v.z);
    atomicAdd(dst + 3, w * v.w);
}

// ---------------------------------------------------------------- batchnorm
__global__ void bn_stats(const float* __restrict__ h, float* __restrict__ stats)
{
    __shared__ float s1[256], s2[256];
    int c = threadIdx.x & 127;
    int half = threadIdx.x >> 7;
    float sum = 0.f, sq = 0.f;
    for (int n = blockIdx.x * 2 + half; n < NN; n += 512) {
        float v = h[n * 128 + c];
        sum += v; sq += v * v;
    }
    s1[threadIdx.x] = sum; s2[threadIdx.x] = sq;
    __syncthreads();
    if (half == 0) {
        s1[c] += s1[c + 128]; s2[c] += s2[c + 128];
        atomicAdd(&stats[c],        s1[c]);
        atomicAdd(&stats[c + 128],  s2[c]);
    }
}

__global__ void bn_apply(float* __restrict__ h, const float* __restrict__ stats,
                         const float* __restrict__ g, const float* __restrict__ b)
{
    int idx = blockIdx.x * 256 + threadIdx.x;
    if (idx >= NN * 128) return;
    int c = idx & 127;
    float mu  = stats[c] * (1.0f / NN);
    float var = stats[c + 128] * (1.0f / NN) - mu * mu;
    h[idx] = (h[idx] - mu) * rsqrtf(var + LN_EPS) * g[c] + b[c];
}

// ---------------------------------------------------------------- launcher
extern "C" void kernel_launch(void* const* d_in, const int* in_sizes, int n_in,
                              void* d_out, int out_size, void* d_ws, size_t ws_size,
                              hipStream_t stream)
{
    auto F = [&](int i) { return (const float*)d_in[i]; };
    const float* x  = F(0);
    const int*   ei = (const int*)d_in[1];
    const float* bn_g = F(23);
    const float* bn_b = F(24);
    // per-conv params: base = 2 + 7*i : ln_g, ln_b, sw, sb, bw, bb, bias

    float* ws    = (float*)d_ws;
    float* dis   = ws;                    // NN
    float* hw    = dis + 50000;           // NN*128 (also holds NN*40 for conv2)
    float* h1    = hw  + 6400000;         // NN*128
    float* h2    = h1  + 6400000;         // NN*128
    float* stats = h2  + 6400000;         // 256
    float* wt0   = stats + 256;           // 640*128
    float* wt1   = wt0 + 81920;           // 640*128
    float* wt2   = wt1 + 81920;           // 1920*40
    float* outf  = (float*)d_out;

    // degree -> dis
    hipMemsetAsync(dis, 0, 50000 * sizeof(float), stream);
    deg_kernel<<<(NE + 255) / 256, 256, 0, stream>>>(ei + NE, dis);
    dis_kernel<<<(NN + 255) / 256, 256, 0, stream>>>(dis);

    // pack weights
    pack_weights<<<(81920 + 255) / 256, 256, 0, stream>>>(F(4),  F(6),  wt0, 128, 128);
    pack_weights<<<(81920 + 255) / 256, 256, 0, stream>>>(F(11), F(13), wt1, 128, 128);
    pack_weights<<<(76800 + 255) / 256, 256, 0, stream>>>(F(18), F(20), wt2, 384, 40);

    const int gridNF = (NN * 128 + 255) / 256;

    // ---- conv0: x -> h1
    fkan_kernel<128, 128><<<NN / 8, 128, 0, stream>>>(x, nullptr, nullptr,
        F(2), F(3), wt0, F(5), F(7), hw);
    agg_init<128><<<gridNF, 256, 0, stream>>>(dis, hw, F(8), h1);
    edge_kernel<128><<<(NE * 32 + 255) / 256, 256, 0, stream>>>(ei, dis, hw, h1);
    hipMemsetAsync(stats, 0, 256 * sizeof(float), stream);
    bn_stats<<<256, 256, 0, stream>>>(h1, stats);
    bn_apply<<<gridNF, 256, 0, stream>>>(h1, stats, bn_g, bn_b);

    // ---- conv1: h1 -> h2
    fkan_kernel<128, 128><<<NN / 8, 128, 0, stream>>>(h1, nullptr, nullptr,
        F(9), F(10), wt1, F(12), F(14), hw);
    agg_init<128><<<gridNF, 256, 0, stream>>>(dis, hw, F(15), h2);
    edge_kernel<128><<<(NE * 32 + 255) / 256, 256, 0, stream>>>(ei, dis, hw, h2);
    hipMemsetAsync(stats, 0, 256 * sizeof(float), stream);
    bn_stats<<<256, 256, 0, stream>>>(h2, stats);
    bn_apply<<<gridNF, 256, 0, stream>>>(h2, stats, bn_g, bn_b);

    // ---- conv2: [x|h1|h2] -> d_out
    fkan_kernel<384, 40><<<NN / 8, 128, 0, stream>>>(x, h1, h2,
        F(16), F(17), wt2, F(19), F(21), hw);
    agg_init<40><<<(NN * 40 + 255) / 256, 256, 0, stream>>>(dis, hw, F(22), outf);
    edge_kernel<40><<<(NE * 10 + 319) / 320, 320, 0, stream>>>(ei, dis, hw, outf);
}

// Round 2
// 1504.924 us; speedup vs baseline: 4.9426x; 4.9426x over previous
//
#include <hip/hip_runtime.h>
#include <math.h>

constexpr int NN = 50000;
constexpr int NE = 1600000;
constexpr float LN_EPS = 1e-5f;

// ---------------------------------------------------------------- degree (int)
__global__ void degi_kernel(const int* __restrict__ col, int* __restrict__ deg)
{
    int e = blockIdx.x * 256 + threadIdx.x;
    if (e < NE) atomicAdd(&deg[col[e]], 1);
}

__global__ void dis_kernel(const int* __restrict__ degi, float* __restrict__ dis)
{
    int i = blockIdx.x * 256 + threadIdx.x;
    if (i < NN) dis[i] = rsqrtf((float)degi[i] + 1.0f);   // +1 = self loop
}

// ---------------------------------------------------------------- exclusive scan (single block)
__global__ __launch_bounds__(1024) void scan_kernel(const int* __restrict__ deg,
                                                    int* __restrict__ off)
{
    __shared__ int part[1024];
    const int t = threadIdx.x;
    constexpr int CH = (NN + 1023) / 1024;     // 49
    const int base = t * CH;
    int s = 0;
    for (int j = 0; j < CH; ++j) { int i = base + j; if (i < NN) s += deg[i]; }
    part[t] = s;
    __syncthreads();
    // inclusive Hillis-Steele
    for (int d = 1; d < 1024; d <<= 1) {
        int add = (t >= d) ? part[t - d] : 0;
        __syncthreads();
        part[t] += add;
        __syncthreads();
    }
    int run = part[t] - s;                      // exclusive prefix for this chunk
    for (int j = 0; j < CH; ++j) {
        int i = base + j;
        if (i < NN) { off[i] = run; run += deg[i]; }
    }
    if (t == 1023) off[NN] = part[1023];
}

// ---------------------------------------------------------------- CSR fill
__global__ void csr_fill(const int* __restrict__ ei, const int* __restrict__ off,
                         int* __restrict__ cur, int* __restrict__ rows)
{
    int e = blockIdx.x * 256 + threadIdx.x;
    if (e >= NE) return;
    int r = ei[e];
    int c = ei[NE + e];
    int p = off[c] + atomicAdd(&cur[c], 1);
    rows[p] = r;
}

// ---------------------------------------------------------------- weight pack
// Wt[k*DO + o], k = f*5 + g ; g<4 -> sw[o][f*4+g], g==4 -> bw[o][f]
__global__ void pack_weights(const float* __restrict__ sw, const float* __restrict__ bw,
                             float* __restrict__ wt, int D, int DO)
{
    int idx = blockIdx.x * 256 + threadIdx.x;
    int K = D * 5;
    if (idx >= K * DO) return;
    int k = idx / DO, o = idx - k * DO;
    int f = k / 5,  g = k - f * 5;
    wt[idx] = (g < 4) ? sw[o * D * 4 + f * 4 + g] : bw[o * D + f];
}

// ---------------------------------------------------------------- FastKAN layer
// block = 128 threads, 8 nodes/block. D multiple of 128, sources are 128-wide.
template<int D, int DO>
__global__ __launch_bounds__(128) void fkan_kernel(
    const float* __restrict__ s0, const float* __restrict__ s1, const float* __restrict__ s2,
    const float* __restrict__ ln_g, const float* __restrict__ ln_b,
    const float* __restrict__ wt, const float* __restrict__ sb, const float* __restrict__ bb,
    float* __restrict__ out)
{
    constexpr int K  = D * 5;
    constexpr int NB = 8;
    __shared__ float feat[K * NB];           // feat[k*8 + node]
    const int tid   = threadIdx.x;
    const int node0 = blockIdx.x * NB;

    // ---- phase 1: LN + RBF basis + SiLU into LDS (16 lanes per node)
    {
        const int ng   = tid >> 4;
        const int ln   = tid & 15;
        const int node = node0 + ng;
        constexpr int FPT = D / 16;
        float v[FPT];
        float sum = 0.f;
        #pragma unroll
        for (int j = 0; j < FPT; ++j) {
            int f = ln * FPT + j;
            const float* s = (D == 128) ? s0 : ((f < 128) ? s0 : (f < 256) ? s1 : s2);
            v[j] = s[node * 128 + (f & 127)];
            sum += v[j];
        }
        #pragma unroll
        for (int m = 1; m < 16; m <<= 1) sum += __shfl_xor(sum, m);
        float mu = sum * (1.0f / D);
        float var = 0.f;
        #pragma unroll
        for (int j = 0; j < FPT; ++j) { float d = v[j] - mu; var += d * d; }
        #pragma unroll
        for (int m = 1; m < 16; m <<= 1) var += __shfl_xor(var, m);
        float rstd = rsqrtf(var * (1.0f / D) + LN_EPS);
        #pragma unroll
        for (int j = 0; j < FPT; ++j) {
            int f = ln * FPT + j;
            float hn = (v[j] - mu) * rstd * ln_g[f] + ln_b[f];
            float* fp = &feat[(f * 5) * NB + ng];
            #pragma unroll
            for (int g = 0; g < 4; ++g) {
                float t = (hn - (-2.0f + (4.0f / 3.0f) * g)) * 0.75f;   // /DENOM
                fp[g * NB] = __expf(-t * t);
            }
            fp[4 * NB] = v[j] / (1.0f + __expf(-v[j]));                 // silu(raw h)
        }
    }
    __syncthreads();

    // ---- phase 2: out[n][o] = feat[n] . Wt[:,o] + sb[o] + bb[o]
    if constexpr (DO == 128) {
        const int o = tid;
        float acc[8] = {0, 0, 0, 0, 0, 0, 0, 0};
        for (int k = 0; k < K; ++k) {
            float w = wt[k * DO + o];
            float4 fa = *(const float4*)&feat[k * 8];
            float4 fb = *(const float4*)&feat[k * 8 + 4];
            acc[0] += fa.x * w; acc[1] += fa.y * w; acc[2] += fa.z * w; acc[3] += fa.w * w;
            acc[4] += fb.x * w; acc[5] += fb.y * w; acc[6] += fb.z * w; acc[7] += fb.w * w;
        }
        float c = sb[o] + bb[o];
        #pragma unroll
        for (int n = 0; n < 8; ++n) out[(node0 + n) * DO + o] = acc[n] + c;
    } else {
        if (tid < 2 * DO) {
            const int o    = tid % DO;
            const int half = tid / DO;
            float acc[4] = {0, 0, 0, 0};
            for (int k = 0; k < K; ++k) {
                float w = wt[k * DO + o];
                float4 fa = *(const float4*)&feat[k * 8 + half * 4];
                acc[0] += fa.x * w; acc[1] += fa.y * w; acc[2] += fa.z * w; acc[3] += fa.w * w;
            }
            float c = sb[o] + bb[o];
            #pragma unroll
            for (int n = 0; n < 4; ++n) out[(node0 + half * 4 + n) * DO + o] = acc[n] + c;
        }
    }
}

// ---------------------------------------------------------------- CSR gather aggregation
// one block per destination node; thread = output channel. Fuses self-loop + bias.
template<int DO, int BLK>
__global__ __launch_bounds__(BLK) void agg_gather(
    const int* __restrict__ off, const int* __restrict__ rows,
    const float* __restrict__ dis, const float* __restrict__ hw,
    const float* __restrict__ bias, float* __restrict__ out)
{
    const int n   = blockIdx.x;
    const int tid = threadIdx.x;
    __shared__ int   srow[BLK];
    __shared__ float swgt[BLK];

    const int e0 = off[n], e1 = off[n + 1];
    const float dn = dis[n];
    float acc = 0.f;
    if (tid < DO) acc = dn * dn * hw[n * DO + tid] + bias[tid];

    for (int t0 = e0; t0 < e1; t0 += BLK) {
        const int nt = min(BLK, e1 - t0);
        if (tid < nt) {
            int r = rows[t0 + tid];
            srow[tid] = r;
            swgt[tid] = dn * dis[r];
        }
        __syncthreads();
        if (tid < DO) {
            #pragma unroll 4
            for (int j = 0; j < nt; ++j)
                acc += swgt[j] * hw[srow[j] * DO + tid];
        }
        __syncthreads();
    }
    if (tid < DO) out[n * DO + tid] = acc;
}

// ---------------------------------------------------------------- batchnorm
__global__ void bn_stats(const float* __restrict__ h, float* __restrict__ stats)
{
    __shared__ float s1[256], s2[256];
    int c = threadIdx.x & 127;
    int half = threadIdx.x >> 7;
    float sum = 0.f, sq = 0.f;
    for (int n = blockIdx.x * 2 + half; n < NN; n += 512) {
        float v = h[n * 128 + c];
        sum += v; sq += v * v;
    }
    s1[threadIdx.x] = sum; s2[threadIdx.x] = sq;
    __syncthreads();
    if (half == 0) {
        s1[c] += s1[c + 128]; s2[c] += s2[c + 128];
        atomicAdd(&stats[c],        s1[c]);
        atomicAdd(&stats[c + 128],  s2[c]);
    }
}

__global__ void bn_apply(float* __restrict__ h, const float* __restrict__ stats,
                         const float* __restrict__ g, const float* __restrict__ b)
{
    int idx = blockIdx.x * 256 + threadIdx.x;
    if (idx >= NN * 128) return;
    int c = idx & 127;
    float mu  = stats[c] * (1.0f / NN);
    float var = stats[c + 128] * (1.0f / NN) - mu * mu;
    h[idx] = (h[idx] - mu) * rsqrtf(var + LN_EPS) * g[c] + b[c];
}

// ---------------------------------------------------------------- launcher
extern "C" void kernel_launch(void* const* d_in, const int* in_sizes, int n_in,
                              void* d_out, int out_size, void* d_ws, size_t ws_size,
                              hipStream_t stream)
{
    auto F = [&](int i) { return (const float*)d_in[i]; };
    const float* x  = F(0);
    const int*   ei = (const int*)d_in[1];
    const float* bn_g = F(23);
    const float* bn_b = F(24);
    // per-conv params: base = 2 + 7*i : ln_g, ln_b, sw, sb, bw, bb, bias

    float* ws    = (float*)d_ws;
    float* dis   = ws;                    // NN
    float* hw    = dis + 50000;           // NN*128 (also holds NN*40 for conv2)
    float* h1    = hw  + 6400000;         // NN*128
    float* h2    = h1  + 6400000;         // NN*128
    float* stats = h2  + 6400000;         // 256
    float* wt0   = stats + 256;           // 640*128
    float* wt1   = wt0 + 81920;           // 640*128
    float* wt2   = wt1 + 81920;           // 1920*40
    int*   degi  = (int*)(wt2 + 76800);   // NN
    int*   off   = degi + 50000;          // NN+1
    int*   cur   = off + 50001;           // NN
    int*   rows  = cur + 50000;           // NE
    float* outf  = (float*)d_out;

    // degree -> dis, CSR build
    hipMemsetAsync(degi, 0, 50000 * sizeof(int), stream);
    hipMemsetAsync(cur,  0, 50000 * sizeof(int), stream);
    degi_kernel<<<(NE + 255) / 256, 256, 0, stream>>>(ei + NE, degi);
    dis_kernel<<<(NN + 255) / 256, 256, 0, stream>>>(degi, dis);
    scan_kernel<<<1, 1024, 0, stream>>>(degi, off);
    csr_fill<<<(NE + 255) / 256, 256, 0, stream>>>(ei, off, cur, rows);

    // pack weights
    pack_weights<<<(81920 + 255) / 256, 256, 0, stream>>>(F(4),  F(6),  wt0, 128, 128);
    pack_weights<<<(81920 + 255) / 256, 256, 0, stream>>>(F(11), F(13), wt1, 128, 128);
    pack_weights<<<(76800 + 255) / 256, 256, 0, stream>>>(F(18), F(20), wt2, 384, 40);

    const int gridNF = (NN * 128 + 255) / 256;

    // ---- conv0: x -> h1
    fkan_kernel<128, 128><<<NN / 8, 128, 0, stream>>>(x, nullptr, nullptr,
        F(2), F(3), wt0, F(5), F(7), hw);
    agg_gather<128, 128><<<NN, 128, 0, stream>>>(off, rows, dis, hw, F(8), h1);
    hipMemsetAsync(stats, 0, 256 * sizeof(float), stream);
    bn_stats<<<256, 256, 0, stream>>>(h1, stats);
    bn_apply<<<gridNF, 256, 0, stream>>>(h1, stats, bn_g, bn_b);

    // ---- conv1: h1 -> h2
    fkan_kernel<128, 128><<<NN / 8, 128, 0, stream>>>(h1, nullptr, nullptr,
        F(9), F(10), wt1, F(12), F(14), hw);
    agg_gather<128, 128><<<NN, 128, 0, stream>>>(off, rows, dis, hw, F(15), h2);
    hipMemsetAsync(stats, 0, 256 * sizeof(float), stream);
    bn_stats<<<256, 256, 0, stream>>>(h2, stats);
    bn_apply<<<gridNF, 256, 0, stream>>>(h2, stats, bn_g, bn_b);

    // ---- conv2: [x|h1|h2] -> d_out
    fkan_kernel<384, 40><<<NN / 8, 128, 0, stream>>>(x, h1, h2,
        F(16), F(17), wt2, F(19), F(21), hw);
    agg_gather<40, 64><<<NN, 64, 0, stream>>>(off, rows, dis, hw, F(22), outf);
}

// Round 3
// 830.578 us; speedup vs baseline: 8.9555x; 1.8119x over previous
//
#include <hip/hip_runtime.h>
#include <math.h>

constexpr int NN = 50000;
constexpr int NE = 1600000;
constexpr float LN_EPS = 1e-5f;

typedef __attribute__((ext_vector_type(8))) short short8;
typedef __attribute__((ext_vector_type(4))) float f32x4;

__device__ __forceinline__ short f2bf(float f)
{
    unsigned u = __builtin_bit_cast(unsigned, f);
    u += 0x7fffu + ((u >> 16) & 1u);          // RNE
    return (short)(u >> 16);
}

// ---------------------------------------------------------------- degree (int)
__global__ void degi_kernel(const int* __restrict__ col, int* __restrict__ deg)
{
    int e = blockIdx.x * 256 + threadIdx.x;
    if (e < NE) atomicAdd(&deg[col[e]], 1);
}

__global__ void dis_kernel(const int* __restrict__ degi, float* __restrict__ dis)
{
    int i = blockIdx.x * 256 + threadIdx.x;
    if (i < NN) dis[i] = rsqrtf((float)degi[i] + 1.0f);   // +1 = self loop
}

// ---------------------------------------------------------------- exclusive scan (single block)
__global__ __launch_bounds__(1024) void scan_kernel(const int* __restrict__ deg,
                                                    int* __restrict__ off)
{
    __shared__ int part[1024];
    const int t = threadIdx.x;
    constexpr int CH = (NN + 1023) / 1024;     // 49
    const int base = t * CH;
    int s = 0;
    for (int j = 0; j < CH; ++j) { int i = base + j; if (i < NN) s += deg[i]; }
    part[t] = s;
    __syncthreads();
    for (int d = 1; d < 1024; d <<= 1) {
        int add = (t >= d) ? part[t - d] : 0;
        __syncthreads();
        part[t] += add;
        __syncthreads();
    }
    int run = part[t] - s;
    for (int j = 0; j < CH; ++j) {
        int i = base + j;
        if (i < NN) { off[i] = run; run += deg[i]; }
    }
    if (t == 1023) off[NN] = part[1023];
}

// ---------------------------------------------------------------- CSR fill
__global__ void csr_fill(const int* __restrict__ ei, const int* __restrict__ off,
                         int* __restrict__ cur, int* __restrict__ rows)
{
    int e = blockIdx.x * 256 + threadIdx.x;
    if (e >= NE) return;
    int r = ei[e];
    int c = ei[NE + e];
    int p = off[c] + atomicAdd(&cur[c], 1);
    rows[p] = r;
}

// ---------------------------------------------------------------- B-fragment pack
// wtf[((kk*OT + ot)*64 + lane)*8 + j8], k = kk*32 + 16*(j8>>2) + 4*(lane>>4) + (j8&3),
// o = ot*16 + (lane&15).  k = f*5+g5 : g5<4 -> sw[o][f*4+g5], g5==4 -> bw[o][f].
__global__ void pack_frag(const float* __restrict__ sw, const float* __restrict__ bw,
                          short* __restrict__ wtf, int D, int OT, int DO, int total)
{
    int idx = blockIdx.x * 256 + threadIdx.x;
    if (idx >= total) return;
    int j8   = idx & 7;
    int lane = (idx >> 3) & 63;
    int rest = idx >> 9;               // kk*OT + ot
    int ot = rest % OT, kk = rest / OT;
    int k = kk * 32 + ((j8 >> 2) * 16) + ((lane >> 4) * 4) + (j8 & 3);
    int o = ot * 16 + (lane & 15);
    int f = k / 5, g5 = k - f * 5;
    float val = 0.f;
    if (o < DO) val = (g5 < 4) ? sw[o * D * 4 + f * 4 + g5] : bw[o * D + f];
    wtf[idx] = f2bf(val);
}

// ---------------------------------------------------------------- FastKAN layer (MFMA)
// 512 threads = 8 waves, 32 nodes/block. Phase 1: LN+RBF+SiLU -> bf16 A-frags in LDS.
// Phase 2: mfma_f32_16x16x32_bf16 over K, B-frags streamed from global (pre-packed).
template<int D, int DO, int OT, int KKC, int NCH>
__global__ __launch_bounds__(512) void fkan_mfma(
    const float* __restrict__ s0, const float* __restrict__ s1, const float* __restrict__ s2,
    const float* __restrict__ ln_g, const float* __restrict__ ln_b,
    const short* __restrict__ wtf, const float* __restrict__ sb, const float* __restrict__ bb,
    float* __restrict__ out)
{
    constexpr int FPT = D / 16;        // features per lane
    constexpr int JPC = FPT / NCH;     // features per chunk
    __shared__ __align__(16) short fragA[KKC * 2 * 64 * 8];

    const int tid  = threadIdx.x;
    const int l16  = tid & 15;
    const int node = tid >> 4;                     // 0..31
    const int gnode = blockIdx.x * 32 + node;
    const int snode = (gnode < NN) ? gnode : (NN - 1);

    // ---- LN stats (full row held in registers)
    float v[FPT];
    float sum = 0.f;
    #pragma unroll
    for (int j = 0; j < FPT; ++j) {
        int f = j * 16 + l16;
        const float* s = (D == 128) ? s0 : ((f < 128) ? s0 : (f < 256) ? s1 : s2);
        v[j] = s[snode * 128 + (f & 127)];
        sum += v[j];
    }
    #pragma unroll
    for (int m = 1; m < 16; m <<= 1) sum += __shfl_xor(sum, m);
    float mu = sum * (1.0f / D);
    float var = 0.f;
    #pragma unroll
    for (int j = 0; j < FPT; ++j) { float d = v[j] - mu; var += d * d; }
    #pragma unroll
    for (int m = 1; m < 16; m <<= 1) var += __shfl_xor(var, m);
    float rstd = rsqrtf(var * (1.0f / D) + LN_EPS);

    const int wave = tid >> 6, lane = tid & 63;
    f32x4 acc0 = {0.f, 0.f, 0.f, 0.f};
    f32x4 acc1 = {0.f, 0.f, 0.f, 0.f};

    for (int ch = 0; ch < NCH; ++ch) {
        if (ch) __syncthreads();                  // prev phase-2 readers done
        // ---- phase 1: write this chunk's A-fragments
        for (int j = ch * JPC; j < (ch + 1) * JPC; ++j) {
            int f = j * 16 + l16;
            float hn = (v[j] - mu) * rstd * ln_g[f] + ln_b[f];
            int k0 = f * 5 - ch * (KKC * 32);
            #pragma unroll
            for (int g = 0; g < 5; ++g) {
                float val;
                if (g < 4) { float t = (hn - (-2.0f + 1.3333333333f * g)) * 0.75f; val = __expf(-t * t); }
                else       { val = v[j] / (1.0f + __expf(-v[j])); }
                int kl = k0 + g;
                int kk = kl >> 5, r = kl & 31;
                int j8 = ((r >> 4) << 2) + (r & 3);
                int g4 = (r & 15) >> 2;
                int idx = ((kk * 2 + (node >> 4)) * 64 + g4 * 16 + (node & 15)) * 8 + j8;
                fragA[idx] = f2bf(val);
            }
        }
        __syncthreads();
        // ---- phase 2: MFMA accumulate
        if (OT == 8) {                             // DO=128, NCH==1
            const int at = wave & 1, ot0 = (wave >> 1) * 2;
            for (int kk = 0; kk < KKC; ++kk) {
                short8 a  = *(const short8*)&fragA[((kk * 2 + at) * 64 + lane) * 8];
                short8 b0 = *(const short8*)&wtf[((kk * 8 + ot0)     * 64 + lane) * 8];
                short8 b1 = *(const short8*)&wtf[((kk * 8 + ot0 + 1) * 64 + lane) * 8];
                acc0 = __builtin_amdgcn_mfma_f32_16x16x32_bf16(a, b0, acc0, 0, 0, 0);
                acc1 = __builtin_amdgcn_mfma_f32_16x16x32_bf16(a, b1, acc1, 0, 0, 0);
            }
        } else {                                   // OT=3, DO=40
            if (wave < 6) {
                const int at = wave & 1, ot = wave >> 1;
                for (int kkl = 0; kkl < KKC; ++kkl) {
                    int kk = ch * KKC + kkl;
                    short8 a = *(const short8*)&fragA[((kkl * 2 + at) * 64 + lane) * 8];
                    short8 b = *(const short8*)&wtf[((kk * 3 + ot) * 64 + lane) * 8];
                    acc0 = __builtin_amdgcn_mfma_f32_16x16x32_bf16(a, b, acc0, 0, 0, 0);
                }
            }
        }
    }

    // ---- epilogue: C write (+sb+bb), C/D layout: col=lane&15, row=(lane>>4)*4+reg
    const int c15 = lane & 15;
    if (OT == 8) {
        const int at = wave & 1, ot0 = (wave >> 1) * 2;
        const int nrow0 = blockIdx.x * 32 + at * 16 + (lane >> 4) * 4;
        const int o0 = ot0 * 16 + c15, o1 = o0 + 16;
        const float cb0 = sb[o0] + bb[o0], cb1 = sb[o1] + bb[o1];
        #pragma unroll
        for (int r = 0; r < 4; ++r) {
            int nr = nrow0 + r;
            if (nr < NN) {
                out[nr * DO + o0] = acc0[r] + cb0;
                out[nr * DO + o1] = acc1[r] + cb1;
            }
        }
    } else {
        if (wave < 6) {
            const int at = wave & 1, ot = wave >> 1;
            const int o = ot * 16 + c15;
            if (o < DO) {
                const int nrow0 = blockIdx.x * 32 + at * 16 + (lane >> 4) * 4;
                const float cb = sb[o] + bb[o];
                #pragma unroll
                for (int r = 0; r < 4; ++r) {
                    int nr = nrow0 + r;
                    if (nr < NN) out[nr * DO + o] = acc0[r] + cb;
                }
            }
        }
    }
}

// ---------------------------------------------------------------- CSR gather aggregation
template<int DO, int BLK>
__global__ __launch_bounds__(BLK) void agg_gather(
    const int* __restrict__ off, const int* __restrict__ rows,
    const float* __restrict__ dis, const float* __restrict__ hw,
    const float* __restrict__ bias, float* __restrict__ out)
{
    const int n   = blockIdx.x;
    const int tid = threadIdx.x;
    __shared__ int   srow[BLK];
    __shared__ float swgt[BLK];

    const int e0 = off[n], e1 = off[n + 1];
    const float dn = dis[n];
    float acc = 0.f;
    if (tid < DO) acc = dn * dn * hw[n * DO + tid] + bias[tid];

    for (int t0 = e0; t0 < e1; t0 += BLK) {
        const int nt = min(BLK, e1 - t0);
        if (tid < nt) {
            int r = rows[t0 + tid];
            srow[tid] = r;
            swgt[tid] = dn * dis[r];
        }
        __syncthreads();
        if (tid < DO) {
            #pragma unroll 4
            for (int j = 0; j < nt; ++j)
                acc += swgt[j] * hw[srow[j] * DO + tid];
        }
        __syncthreads();
    }
    if (tid < DO) out[n * DO + tid] = acc;
}

// ---------------------------------------------------------------- batchnorm
__global__ void bn_stats(const float* __restrict__ h, float* __restrict__ stats)
{
    __shared__ float s1[256], s2[256];
    int c = threadIdx.x & 127;
    int half = threadIdx.x >> 7;
    float sum = 0.f, sq = 0.f;
    for (int n = blockIdx.x * 2 + half; n < NN; n += 512) {
        float v = h[n * 128 + c];
        sum += v; sq += v * v;
    }
    s1[threadIdx.x] = sum; s2[threadIdx.x] = sq;
    __syncthreads();
    if (half == 0) {
        s1[c] += s1[c + 128]; s2[c] += s2[c + 128];
        atomicAdd(&stats[c],        s1[c]);
        atomicAdd(&stats[c + 128],  s2[c]);
    }
}

__global__ void bn_apply(float* __restrict__ h, const float* __restrict__ stats,
                         const float* __restrict__ g, const float* __restrict__ b)
{
    int idx = blockIdx.x * 256 + threadIdx.x;
    if (idx >= NN * 128) return;
    int c = idx & 127;
    float mu  = stats[c] * (1.0f / NN);
    float var = stats[c + 128] * (1.0f / NN) - mu * mu;
    h[idx] = (h[idx] - mu) * rsqrtf(var + LN_EPS) * g[c] + b[c];
}

// ---------------------------------------------------------------- launcher
extern "C" void kernel_launch(void* const* d_in, const int* in_sizes, int n_in,
                              void* d_out, int out_size, void* d_ws, size_t ws_size,
                              hipStream_t stream)
{
    auto F = [&](int i) { return (const float*)d_in[i]; };
    const float* x  = F(0);
    const int*   ei = (const int*)d_in[1];
    const float* bn_g = F(23);
    const float* bn_b = F(24);
    // per-conv params: base = 2 + 7*i : ln_g, ln_b, sw, sb, bw, bb, bias

    // ---- workspace layout (wtf first for 16B alignment)
    short* wtf0 = (short*)d_ws;                 // 20*8*64*8  = 81920 shorts
    short* wtf1 = wtf0 + 81920;                 // 81920
    short* wtf2 = wtf1 + 81920;                 // 60*3*64*8  = 92160
    float* dis  = (float*)(wtf2 + 92160);       // NN
    float* hw   = dis + 50000;                  // NN*128 (NN*40 for conv2)
    float* h1   = hw  + 6400000;
    float* h2   = h1  + 6400000;
    float* stats = h2 + 6400000;                // 256
    int*   degi = (int*)(stats + 256);          // NN
    int*   off  = degi + 50000;                 // NN+1
    int*   cur  = off + 50001;                  // NN
    int*   rows = cur + 50000;                  // NE
    float* outf = (float*)d_out;

    // ---- degree -> dis, CSR build
    hipMemsetAsync(degi, 0, 50000 * sizeof(int), stream);
    hipMemsetAsync(cur,  0, 50000 * sizeof(int), stream);
    degi_kernel<<<(NE + 255) / 256, 256, 0, stream>>>(ei + NE, degi);
    dis_kernel<<<(NN + 255) / 256, 256, 0, stream>>>(degi, dis);
    scan_kernel<<<1, 1024, 0, stream>>>(degi, off);
    csr_fill<<<(NE + 255) / 256, 256, 0, stream>>>(ei, off, cur, rows);

    // ---- pack B fragments (bf16)
    pack_frag<<<(81920 + 255) / 256, 256, 0, stream>>>(F(4),  F(6),  wtf0, 128, 8, 128, 81920);
    pack_frag<<<(81920 + 255) / 256, 256, 0, stream>>>(F(11), F(13), wtf1, 128, 8, 128, 81920);
    pack_frag<<<(92160 + 255) / 256, 256, 0, stream>>>(F(18), F(20), wtf2, 384, 3, 40,  92160);

    const int gridN = (NN + 31) / 32;           // 1563
    const int gridNF = (NN * 128 + 255) / 256;

    // ---- conv0: x -> h1
    fkan_mfma<128, 128, 8, 20, 1><<<gridN, 512, 0, stream>>>(x, nullptr, nullptr,
        F(2), F(3), wtf0, F(5), F(7), hw);
    agg_gather<128, 128><<<NN, 128, 0, stream>>>(off, rows, dis, hw, F(8), h1);
    hipMemsetAsync(stats, 0, 256 * sizeof(float), stream);
    bn_stats<<<256, 256, 0, stream>>>(h1, stats);
    bn_apply<<<gridNF, 256, 0, stream>>>(h1, stats, bn_g, bn_b);

    // ---- conv1: h1 -> h2
    fkan_mfma<128, 128, 8, 20, 1><<<gridN, 512, 0, stream>>>(h1, nullptr, nullptr,
        F(9), F(10), wtf1, F(12), F(14), hw);
    agg_gather<128, 128><<<NN, 128, 0, stream>>>(off, rows, dis, hw, F(15), h2);
    hipMemsetAsync(stats, 0, 256 * sizeof(float), stream);
    bn_stats<<<256, 256, 0, stream>>>(h2, stats);
    bn_apply<<<gridNF, 256, 0, stream>>>(h2, stats, bn_g, bn_b);

    // ---- conv2: [x|h1|h2] -> d_out
    fkan_mfma<384, 40, 3, 30, 2><<<gridN, 512, 0, stream>>>(x, h1, h2,
        F(16), F(17), wtf2, F(19), F(21), hw);
    agg_gather<40, 64><<<NN, 64, 0, stream>>>(off, rows, dis, hw, F(22), outf);
}

// Round 4
// 653.565 us; speedup vs baseline: 11.3810x; 1.2708x over previous
//
#include <hip/hip_runtime.h>
#include <math.h>

constexpr int NN = 50000;
constexpr int NE = 1600000;
constexpr float LN_EPS = 1e-5f;

typedef __attribute__((ext_vector_type(8))) short short8;
typedef __attribute__((ext_vector_type(4))) float f32x4;

__device__ __forceinline__ short f2bf(float f)
{
    unsigned u = __builtin_bit_cast(unsigned, f);
    u += 0x7fffu + ((u >> 16) & 1u);          // RNE
    return (short)(u >> 16);
}

__device__ __forceinline__ float2 bf2x2(unsigned p)
{
    float2 r;
    r.x = __builtin_bit_cast(float, p << 16);          // low ushort
    r.y = __builtin_bit_cast(float, p & 0xffff0000u);  // high ushort
    return r;
}

// ---------------------------------------------------------------- degree (int)
__global__ void degi_kernel(const int* __restrict__ col, int* __restrict__ deg)
{
    int e = blockIdx.x * 256 + threadIdx.x;
    if (e < NE) atomicAdd(&deg[col[e]], 1);
}

__global__ void dis_kernel(const int* __restrict__ degi, float* __restrict__ dis)
{
    int i = blockIdx.x * 256 + threadIdx.x;
    if (i < NN) dis[i] = rsqrtf((float)degi[i] + 1.0f);   // +1 = self loop
}

// ---------------------------------------------------------------- exclusive scan (single block)
__global__ __launch_bounds__(1024) void scan_kernel(const int* __restrict__ deg,
                                                    int* __restrict__ off)
{
    __shared__ int part[1024];
    const int t = threadIdx.x;
    constexpr int CH = (NN + 1023) / 1024;     // 49
    const int base = t * CH;
    int s = 0;
    for (int j = 0; j < CH; ++j) { int i = base + j; if (i < NN) s += deg[i]; }
    part[t] = s;
    __syncthreads();
    for (int d = 1; d < 1024; d <<= 1) {
        int add = (t >= d) ? part[t - d] : 0;
        __syncthreads();
        part[t] += add;
        __syncthreads();
    }
    int run = part[t] - s;
    for (int j = 0; j < CH; ++j) {
        int i = base + j;
        if (i < NN) { off[i] = run; run += deg[i]; }
    }
    if (t == 1023) off[NN] = part[1023];
}

// ---------------------------------------------------------------- CSR fill
__global__ void csr_fill(const int* __restrict__ ei, const int* __restrict__ off,
                         int* __restrict__ cur, int* __restrict__ rows)
{
    int e = blockIdx.x * 256 + threadIdx.x;
    if (e >= NE) return;
    int r = ei[e];
    int c = ei[NE + e];
    int p = off[c] + atomicAdd(&cur[c], 1);
    rows[p] = r;
}

// ---------------------------------------------------------------- B-fragment pack
__global__ void pack_frag(const float* __restrict__ sw, const float* __restrict__ bw,
                          short* __restrict__ wtf, int D, int OT, int DO, int total)
{
    int idx = blockIdx.x * 256 + threadIdx.x;
    if (idx >= total) return;
    int j8   = idx & 7;
    int lane = (idx >> 3) & 63;
    int rest = idx >> 9;               // kk*OT + ot
    int ot = rest % OT, kk = rest / OT;
    int k = kk * 32 + ((j8 >> 2) * 16) + ((lane >> 4) * 4) + (j8 & 3);
    int o = ot * 16 + (lane & 15);
    int f = k / 5, g5 = k - f * 5;
    float val = 0.f;
    if (o < DO) val = (g5 < 4) ? sw[o * D * 4 + f * 4 + g5] : bw[o * D + f];
    wtf[idx] = f2bf(val);
}

// ---------------------------------------------------------------- FastKAN layer (MFMA)
// 512 threads = 8 waves, 32 nodes/block. Output written as bf16 (gather payload).
template<int D, int DO, int OT, int KKC, int NCH>
__global__ __launch_bounds__(512) void fkan_mfma(
    const float* __restrict__ s0, const float* __restrict__ s1, const float* __restrict__ s2,
    const float* __restrict__ ln_g, const float* __restrict__ ln_b,
    const short* __restrict__ wtf, const float* __restrict__ sb, const float* __restrict__ bb,
    short* __restrict__ out)
{
    constexpr int FPT = D / 16;        // features per lane
    constexpr int JPC = FPT / NCH;     // features per chunk
    __shared__ __align__(16) short fragA[KKC * 2 * 64 * 8];

    const int tid  = threadIdx.x;
    const int l16  = tid & 15;
    const int node = tid >> 4;                     // 0..31
    const int gnode = blockIdx.x * 32 + node;
    const int snode = (gnode < NN) ? gnode : (NN - 1);

    // ---- LN stats (full row held in registers)
    float v[FPT];
    float sum = 0.f;
    #pragma unroll
    for (int j = 0; j < FPT; ++j) {
        int f = j * 16 + l16;
        const float* s = (D == 128) ? s0 : ((f < 128) ? s0 : (f < 256) ? s1 : s2);
        v[j] = s[snode * 128 + (f & 127)];
        sum += v[j];
    }
    #pragma unroll
    for (int m = 1; m < 16; m <<= 1) sum += __shfl_xor(sum, m);
    float mu = sum * (1.0f / D);
    float var = 0.f;
    #pragma unroll
    for (int j = 0; j < FPT; ++j) { float d = v[j] - mu; var += d * d; }
    #pragma unroll
    for (int m = 1; m < 16; m <<= 1) var += __shfl_xor(var, m);
    float rstd = rsqrtf(var * (1.0f / D) + LN_EPS);

    const int wave = tid >> 6, lane = tid & 63;
    f32x4 acc0 = {0.f, 0.f, 0.f, 0.f};
    f32x4 acc1 = {0.f, 0.f, 0.f, 0.f};

    for (int ch = 0; ch < NCH; ++ch) {
        if (ch) __syncthreads();                  // prev phase-2 readers done
        // ---- phase 1: write this chunk's A-fragments
        for (int j = ch * JPC; j < (ch + 1) * JPC; ++j) {
            int f = j * 16 + l16;
            float hn = (v[j] - mu) * rstd * ln_g[f] + ln_b[f];
            int k0 = f * 5 - ch * (KKC * 32);
            #pragma unroll
            for (int g = 0; g < 5; ++g) {
                float val;
                if (g < 4) { float t = (hn - (-2.0f + 1.3333333333f * g)) * 0.75f; val = __expf(-t * t); }
                else       { val = v[j] / (1.0f + __expf(-v[j])); }
                int kl = k0 + g;
                int kk = kl >> 5, r = kl & 31;
                int j8 = ((r >> 4) << 2) + (r & 3);
                int g4 = (r & 15) >> 2;
                int idx = ((kk * 2 + (node >> 4)) * 64 + g4 * 16 + (node & 15)) * 8 + j8;
                fragA[idx] = f2bf(val);
            }
        }
        __syncthreads();
        // ---- phase 2: MFMA accumulate
        if (OT == 8) {                             // DO=128, NCH==1
            const int at = wave & 1, ot0 = (wave >> 1) * 2;
            for (int kk = 0; kk < KKC; ++kk) {
                short8 a  = *(const short8*)&fragA[((kk * 2 + at) * 64 + lane) * 8];
                short8 b0 = *(const short8*)&wtf[((kk * 8 + ot0)     * 64 + lane) * 8];
                short8 b1 = *(const short8*)&wtf[((kk * 8 + ot0 + 1) * 64 + lane) * 8];
                acc0 = __builtin_amdgcn_mfma_f32_16x16x32_bf16(a, b0, acc0, 0, 0, 0);
                acc1 = __builtin_amdgcn_mfma_f32_16x16x32_bf16(a, b1, acc1, 0, 0, 0);
            }
        } else {                                   // OT=3, DO=40
            if (wave < 6) {
                const int at = wave & 1, ot = wave >> 1;
                for (int kkl = 0; kkl < KKC; ++kkl) {
                    int kk = ch * KKC + kkl;
                    short8 a = *(const short8*)&fragA[((kkl * 2 + at) * 64 + lane) * 8];
                    short8 b = *(const short8*)&wtf[((kk * 3 + ot) * 64 + lane) * 8];
                    acc0 = __builtin_amdgcn_mfma_f32_16x16x32_bf16(a, b, acc0, 0, 0, 0);
                }
            }
        }
    }

    // ---- epilogue: bf16 write (+sb+bb), C/D layout: col=lane&15, row=(lane>>4)*4+reg
    const int c15 = lane & 15;
    if (OT == 8) {
        const int at = wave & 1, ot0 = (wave >> 1) * 2;
        const int nrow0 = blockIdx.x * 32 + at * 16 + (lane >> 4) * 4;
        const int o0 = ot0 * 16 + c15, o1 = o0 + 16;
        const float cb0 = sb[o0] + bb[o0], cb1 = sb[o1] + bb[o1];
        #pragma unroll
        for (int r = 0; r < 4; ++r) {
            int nr = nrow0 + r;
            if (nr < NN) {
                out[nr * DO + o0] = f2bf(acc0[r] + cb0);
                out[nr * DO + o1] = f2bf(acc1[r] + cb1);
            }
        }
    } else {
        if (wave < 6) {
            const int at = wave & 1, ot = wave >> 1;
            const int o = ot * 16 + c15;
            if (o < DO) {
                const int nrow0 = blockIdx.x * 32 + at * 16 + (lane >> 4) * 4;
                const float cb = sb[o] + bb[o];
                #pragma unroll
                for (int r = 0; r < 4; ++r) {
                    int nr = nrow0 + r;
                    if (nr < NN) out[nr * DO + o] = f2bf(acc0[r] + cb);
                }
            }
        }
    }
}

// ---------------------------------------------------------------- CSR gather (bf16 rows)
// BLK=64, one block per dst node; thread owns 2 channels (one uint load/row).
template<int DO>
__global__ __launch_bounds__(64) void agg_gather_bf16(
    const int* __restrict__ off, const int* __restrict__ rows,
    const float* __restrict__ dis, const short* __restrict__ hwb,
    const float* __restrict__ bias, float* __restrict__ out)
{
    constexpr int ACT = DO / 2;        // active compute lanes
    const int n   = blockIdx.x;
    const int tid = threadIdx.x;
    __shared__ int   srow[64];
    __shared__ float swgt[64];

    const int e0 = off[n], e1 = off[n + 1];
    const float dn = dis[n];
    float ax = 0.f, ay = 0.f;
    if (tid < ACT) {
        unsigned p = *(const unsigned*)&hwb[n * DO + 2 * tid];
        float2 v = bf2x2(p);
        ax = dn * dn * v.x + bias[2 * tid];
        ay = dn * dn * v.y + bias[2 * tid + 1];
    }

    for (int t0 = e0; t0 < e1; t0 += 64) {
        const int nt = min(64, e1 - t0);
        if (tid < nt) {
            int r = rows[t0 + tid];
            srow[tid] = r;
            swgt[tid] = dn * dis[r];
        }
        __syncthreads();
        if (tid < ACT) {
            #pragma unroll 4
            for (int j = 0; j < nt; ++j) {
                unsigned p = *(const unsigned*)&hwb[srow[j] * DO + 2 * tid];
                float2 v = bf2x2(p);
                float w = swgt[j];
                ax += w * v.x;
                ay += w * v.y;
            }
        }
        __syncthreads();
    }
    if (tid < ACT) {
        out[n * DO + 2 * tid]     = ax;
        out[n * DO + 2 * tid + 1] = ay;
    }
}

// ---------------------------------------------------------------- batchnorm
__global__ void bn_stats(const float* __restrict__ h, float* __restrict__ stats)
{
    __shared__ float s1[256], s2[256];
    int c = threadIdx.x & 127;
    int half = threadIdx.x >> 7;
    float sum = 0.f, sq = 0.f;
    for (int n = blockIdx.x * 2 + half; n < NN; n += 512) {
        float v = h[n * 128 + c];
        sum += v; sq += v * v;
    }
    s1[threadIdx.x] = sum; s2[threadIdx.x] = sq;
    __syncthreads();
    if (half == 0) {
        s1[c] += s1[c + 128]; s2[c] += s2[c + 128];
        atomicAdd(&stats[c],        s1[c]);
        atomicAdd(&stats[c + 128],  s2[c]);
    }
}

__global__ void bn_apply(float* __restrict__ h, const float* __restrict__ stats,
                         const float* __restrict__ g, const float* __restrict__ b)
{
    int idx = blockIdx.x * 256 + threadIdx.x;
    if (idx >= NN * 128) return;
    int c = idx & 127;
    float mu  = stats[c] * (1.0f / NN);
    float var = stats[c + 128] * (1.0f / NN) - mu * mu;
    h[idx] = (h[idx] - mu) * rsqrtf(var + LN_EPS) * g[c] + b[c];
}

// ---------------------------------------------------------------- launcher
extern "C" void kernel_launch(void* const* d_in, const int* in_sizes, int n_in,
                              void* d_out, int out_size, void* d_ws, size_t ws_size,
                              hipStream_t stream)
{
    auto F = [&](int i) { return (const float*)d_in[i]; };
    const float* x  = F(0);
    const int*   ei = (const int*)d_in[1];
    const float* bn_g = F(23);
    const float* bn_b = F(24);
    // per-conv params: base = 2 + 7*i : ln_g, ln_b, sw, sb, bw, bb, bias

    // ---- workspace layout
    short* wtf0 = (short*)d_ws;                 // 81920 shorts
    short* wtf1 = wtf0 + 81920;                 // 81920
    short* wtf2 = wtf1 + 81920;                 // 92160
    short* hwb  = wtf2 + 92160;                 // NN*128 bf16 (NN*40 for conv2)
    float* dis  = (float*)(hwb + 6400000);      // NN
    float* h1   = dis + 50000;                  // NN*128
    float* h2   = h1  + 6400000;
    float* stats = h2 + 6400000;                // 256
    int*   degi = (int*)(stats + 256);          // NN
    int*   off  = degi + 50000;                 // NN+1
    int*   cur  = off + 50001;                  // NN
    int*   rows = cur + 50000;                  // NE
    float* outf = (float*)d_out;

    // ---- degree -> dis, CSR build
    hipMemsetAsync(degi, 0, 50000 * sizeof(int), stream);
    hipMemsetAsync(cur,  0, 50000 * sizeof(int), stream);
    degi_kernel<<<(NE + 255) / 256, 256, 0, stream>>>(ei + NE, degi);
    dis_kernel<<<(NN + 255) / 256, 256, 0, stream>>>(degi, dis);
    scan_kernel<<<1, 1024, 0, stream>>>(degi, off);
    csr_fill<<<(NE + 255) / 256, 256, 0, stream>>>(ei, off, cur, rows);

    // ---- pack B fragments (bf16)
    pack_frag<<<(81920 + 255) / 256, 256, 0, stream>>>(F(4),  F(6),  wtf0, 128, 8, 128, 81920);
    pack_frag<<<(81920 + 255) / 256, 256, 0, stream>>>(F(11), F(13), wtf1, 128, 8, 128, 81920);
    pack_frag<<<(92160 + 255) / 256, 256, 0, stream>>>(F(18), F(20), wtf2, 384, 3, 40,  92160);

    const int gridN = (NN + 31) / 32;           // 1563
    const int gridNF = (NN * 128 + 255) / 256;

    // ---- conv0: x -> h1
    fkan_mfma<128, 128, 8, 20, 1><<<gridN, 512, 0, stream>>>(x, nullptr, nullptr,
        F(2), F(3), wtf0, F(5), F(7), hwb);
    agg_gather_bf16<128><<<NN, 64, 0, stream>>>(off, rows, dis, hwb, F(8), h1);
    hipMemsetAsync(stats, 0, 256 * sizeof(float), stream);
    bn_stats<<<256, 256, 0, stream>>>(h1, stats);
    bn_apply<<<gridNF, 256, 0, stream>>>(h1, stats, bn_g, bn_b);

    // ---- conv1: h1 -> h2
    fkan_mfma<128, 128, 8, 20, 1><<<gridN, 512, 0, stream>>>(h1, nullptr, nullptr,
        F(9), F(10), wtf1, F(12), F(14), hwb);
    agg_gather_bf16<128><<<NN, 64, 0, stream>>>(off, rows, dis, hwb, F(15), h2);
    hipMemsetAsync(stats, 0, 256 * sizeof(float), stream);
    bn_stats<<<256, 256, 0, stream>>>(h2, stats);
    bn_apply<<<gridNF, 256, 0, stream>>>(h2, stats, bn_g, bn_b);

    // ---- conv2: [x|h1|h2] -> d_out
    fkan_mfma<384, 40, 3, 30, 2><<<gridN, 512, 0, stream>>>(x, h1, h2,
        F(16), F(17), wtf2, F(19), F(21), hwb);
    agg_gather_bf16<40><<<NN, 64, 0, stream>>>(off, rows, dis, hwb, F(22), outf);
}